// Round 13
// baseline (118.904 us; speedup 1.0000x reference)
//
#include <hip/hip_runtime.h>
#include <hip/hip_bf16.h>

// R13 = ABLATION ROUND. R12 (70.75us, best) + a stage-only pass inserted
// before the real phase 2: identical GLOAD/DSWRITE/vmcnt/barrier pipeline,
// COMPUTE removed. T_ablate = dur - 70.75 decides:
//   <=42us -> stage pipeline sustains ~7TB/s, compute coupling is the cap;
//   >=50us -> lockstep staging structure itself is capped.
// Real pass follows (re-streams adj; 1MB/CU can't stay cached) -> output valid.

#define BATCH 256
#define NTOK  512
#define INF   64
#define OUTF  64

typedef __attribute__((ext_vector_type(8))) __bf16 bf16x8;
typedef __attribute__((ext_vector_type(4))) __bf16 bf16x4;
typedef __attribute__((ext_vector_type(4))) float  f32x4;

__device__ __forceinline__ bf16x8 load_cvt8(const float* __restrict__ p) {
    float4 lo = *(const float4*)p;
    float4 hi = *(const float4*)(p + 4);
    bf16x8 r;
    r[0] = (__bf16)lo.x; r[1] = (__bf16)lo.y; r[2] = (__bf16)lo.z; r[3] = (__bf16)lo.w;
    r[4] = (__bf16)hi.x; r[5] = (__bf16)hi.y; r[6] = (__bf16)hi.z; r[7] = (__bf16)hi.w;
    return r;
}

__device__ __forceinline__ bf16x8 pack8(float4 lo, float4 hi) {
    bf16x8 r;
    r[0] = (__bf16)lo.x; r[1] = (__bf16)lo.y; r[2] = (__bf16)lo.z; r[3] = (__bf16)lo.w;
    r[4] = (__bf16)hi.x; r[5] = (__bf16)hi.y; r[6] = (__bf16)hi.z; r[7] = (__bf16)hi.w;
    return r;
}

__global__ __launch_bounds__(512, 2) void GCN_fused_kernel(
        const float* __restrict__ seq, const float* __restrict__ adj,
        const float* __restrict__ W, const float* __restrict__ bias,
        const float* __restrict__ alpha_p, float* __restrict__ out) {
    __shared__ float smem[32768];            // 128 KB

    int b    = blockIdx.x;
    int tid  = threadIdx.x;
    int wave = tid >> 6;                     // 0..7
    int lane = tid & 63;
    int row16 = lane & 15;
    int g     = lane >> 4;                   // 0..3
    int c     = wave & 3;                    // col-group
    int mt    = wave >> 2;                   // 0/1
    int rs    = row16 & 7;

    __bf16* sft = (__bf16*)smem;             // [64 o][512 k] bf16 (lower 64 KB)
    float* buf0 = smem + 16384;              // even chunks
    float* buf1 = smem;                      // odd chunks (overlays sft)

    const float* gadj = adj + (size_t)b * NTOK * NTOK;

#define GLOAD(RG, rbase) do {                                                  \
    _Pragma("unroll")                                                          \
    for (int i_ = 0; i_ < 8; ++i_) {                                           \
        int idx_ = wave * 8 + i_;                                              \
        (RG)[i_] = *(const f32x4*)(gadj + (size_t)((rbase) + (idx_ >> 1)) * NTOK \
                                   + (idx_ & 1) * 256 + lane * 4);             \
    }                                                                          \
} while (0)

#define DSWRITE(RG, dstf) do {                                                 \
    _Pragma("unroll")                                                          \
    for (int i_ = 0; i_ < 8; ++i_) {                                           \
        int idx_ = wave * 8 + i_;                                              \
        int row_ = idx_ >> 1;                                                  \
        *(f32x4*)((dstf) + idx_ * 256 + ((lane ^ (row_ & 7)) << 2)) = (RG)[i_];\
    }                                                                          \
} while (0)

#define COMPUTE(CIDX, cur) do {                                                \
    f32x4 acc; acc[0] = bv; acc[1] = bv; acc[2] = bv; acc[3] = bv;             \
    int rowb_ = (mt * 16 + row16) * 512;                                       \
    _Pragma("unroll")                                                          \
    for (int ks_ = 0; ks_ < 16; ++ks_) {                                       \
        int s0_ = (ks_ * 8 + g * 2) ^ rs;                                      \
        float4 f0_ = *(const float4*)((cur) + rowb_ + s0_ * 4);                \
        float4 f1_ = *(const float4*)((cur) + rowb_ + (s0_ ^ 1) * 4);          \
        bf16x8 a_ = pack8(f0_, f1_);                                           \
        acc = __builtin_amdgcn_mfma_f32_16x16x32_bf16(a_, bbr[ks_], acc, 0, 0, 0); \
    }                                                                          \
    int m_ = (CIDX) * 32 + mt * 16 + g * 4;                                    \
    float* op_ = out + ((size_t)b * NTOK + m_) * OUTF + orow;                  \
    _Pragma("unroll")                                                          \
    for (int j_ = 0; j_ < 4; ++j_) {                                           \
        float v_ = acc[j_];                                                    \
        op_[(size_t)j_ * OUTF] = (v_ >= 0.f) ? v_ : alphav * v_;               \
    }                                                                          \
} while (0)

// Real body. Audited waits: body0=8, body1=12, bodies 2..14=16, body15=8.
#define BODY(CIDX, CUR, GC, DOLOAD, GN, WAITN) do {                            \
    asm volatile("s_waitcnt vmcnt(" #WAITN ")" ::: "memory");                  \
    __builtin_amdgcn_sched_barrier(0);                                         \
    DSWRITE(GC, CUR);                                                          \
    asm volatile("s_waitcnt lgkmcnt(0)" ::: "memory");                         \
    __builtin_amdgcn_sched_barrier(0);                                         \
    __builtin_amdgcn_s_barrier();                                              \
    __builtin_amdgcn_sched_barrier(0);                                         \
    if (DOLOAD) { GLOAD(GN, ((CIDX) + 2) * 32); }                              \
    __builtin_amdgcn_sched_barrier(0);                                         \
    COMPUTE(CIDX, CUR);                                                        \
} while (0)

// Ablated body: identical minus COMPUTE. No stores -> waits: 8,...,8, last 0.
#define BODYA(CIDX, CUR, GC, DOLOAD, GN, WAITN) do {                           \
    asm volatile("s_waitcnt vmcnt(" #WAITN ")" ::: "memory");                  \
    __builtin_amdgcn_sched_barrier(0);                                         \
    DSWRITE(GC, CUR);                                                          \
    asm volatile("s_waitcnt lgkmcnt(0)" ::: "memory");                         \
    __builtin_amdgcn_sched_barrier(0);                                         \
    __builtin_amdgcn_s_barrier();                                              \
    __builtin_amdgcn_sched_barrier(0);                                         \
    if (DOLOAD) { GLOAD(GN, ((CIDX) + 2) * 32); }                              \
    __builtin_amdgcn_sched_barrier(0);                                         \
} while (0)

    f32x4 g0[8], g1[8], g2[8];
    GLOAD(g0, 0);                            // chunks 0,1 prefetch under phase 1
    GLOAD(g1, 32);
    __builtin_amdgcn_sched_barrier(0);

    // ================= Phase 1: sft[o][k] = (seq @ W^T)^T ===================
    {
        int mb = wave * 64;
        bf16x8 wf[4][2];
#pragma unroll
        for (int nt = 0; nt < 4; ++nt)
#pragma unroll
            for (int ks = 0; ks < 2; ++ks)
                wf[nt][ks] = load_cvt8(W + (size_t)(nt * 16 + row16) * INF + ks * 32 + g * 8);

#pragma unroll
        for (int mt2 = 0; mt2 < 4; ++mt2) {
            f32x4 pa[4] = {};
#pragma unroll
            for (int ks = 0; ks < 2; ++ks) {
                bf16x8 af = load_cvt8(seq + ((size_t)b * NTOK + mb + mt2 * 16 + row16) * INF + ks * 32 + g * 8);
#pragma unroll
                for (int nt = 0; nt < 4; ++nt)
                    pa[nt] = __builtin_amdgcn_mfma_f32_16x16x32_bf16(af, wf[nt][ks], pa[nt], 0, 0, 0);
            }
#pragma unroll
            for (int nt = 0; nt < 4; ++nt) {
                int o    = nt * 16 + row16;
                int ktok = mb + mt2 * 16 + g * 4;
                int sw   = (ktok >> 3) ^ (o & 7);
                bf16x4 v;
                v[0] = (__bf16)pa[nt][0]; v[1] = (__bf16)pa[nt][1];
                v[2] = (__bf16)pa[nt][2]; v[3] = (__bf16)pa[nt][3];
                *(bf16x4*)((char*)sft + (size_t)o * 1024 + sw * 16 + (ktok & 7) * 2) = v;
            }
        }
    }
    int orow     = c * 16 + row16;
    float bv     = bias[orow];
    float alphav = alpha_p[0];
    __syncthreads();

    bf16x8 bbr[16];
#pragma unroll
    for (int t = 0; t < 16; ++t) {
        int sw = ((t << 2) + g) ^ rs;
        bbr[t] = *(const bf16x8*)((const char*)sft + (size_t)orow * 1024 + sw * 16);
    }
    __syncthreads();   // drains all vmem; buf1 reusable

    // ============ ABLATION PASS: stage-only, chunks 0..15 ===================
    BODYA( 0, buf0, g0, 1, g2, 8);
    BODYA( 1, buf1, g1, 1, g0, 8);
    BODYA( 2, buf0, g2, 1, g1, 8);
    BODYA( 3, buf1, g0, 1, g2, 8);
    BODYA( 4, buf0, g1, 1, g0, 8);
    BODYA( 5, buf1, g2, 1, g1, 8);
    BODYA( 6, buf0, g0, 1, g2, 8);
    BODYA( 7, buf1, g1, 1, g0, 8);
    BODYA( 8, buf0, g2, 1, g1, 8);
    BODYA( 9, buf1, g0, 1, g2, 8);
    BODYA(10, buf0, g1, 1, g0, 8);
    BODYA(11, buf1, g2, 1, g1, 8);
    BODYA(12, buf0, g0, 1, g2, 8);
    BODYA(13, buf1, g1, 1, g0, 8);
    BODYA(14, buf0, g2, 0, g0, 8);
    BODYA(15, buf1, g0, 0, g0, 0);

    // ============ re-prime and REAL PASS (produces the output) ==============
    GLOAD(g0, 0);
    GLOAD(g1, 32);
    __builtin_amdgcn_sched_barrier(0);

    BODY( 0, buf0, g0, 1, g2,  8);
    BODY( 1, buf1, g1, 1, g0, 12);
    BODY( 2, buf0, g2, 1, g1, 16);
    BODY( 3, buf1, g0, 1, g2, 16);
    BODY( 4, buf0, g1, 1, g0, 16);
    BODY( 5, buf1, g2, 1, g1, 16);
    BODY( 6, buf0, g0, 1, g2, 16);
    BODY( 7, buf1, g1, 1, g0, 16);
    BODY( 8, buf0, g2, 1, g1, 16);
    BODY( 9, buf1, g0, 1, g2, 16);
    BODY(10, buf0, g1, 1, g0, 16);
    BODY(11, buf1, g2, 1, g1, 16);
    BODY(12, buf0, g0, 1, g2, 16);
    BODY(13, buf1, g1, 1, g0, 16);
    BODY(14, buf0, g2, 0, g0, 16);
    BODY(15, buf1, g0, 0, g0,  8);
#undef BODY
#undef BODYA
#undef GLOAD
#undef DSWRITE
#undef COMPUTE
}

extern "C" void kernel_launch(void* const* d_in, const int* in_sizes, int n_in,
                              void* d_out, int out_size, void* d_ws, size_t ws_size,
                              hipStream_t stream) {
    const float* seq   = (const float*)d_in[0];
    const float* adj   = (const float*)d_in[1];
    const float* W     = (const float*)d_in[2];
    const float* bias  = (const float*)d_in[3];
    const float* alpha = (const float*)d_in[4];
    float* out = (float*)d_out;

    GCN_fused_kernel<<<dim3(BATCH), dim3(512), 0, stream>>>(seq, adj, W, bias, alpha, out);
}

// Round 14
// 73.975 us; speedup vs baseline: 1.6074x; 1.6074x over previous
//
#include <hip/hip_runtime.h>
#include <hip/hip_bf16.h>

// GCN forward FUSED v6 (wave-private, barrier-free phase 2):
//   out = PReLU(adj @ (seq @ W^T) + bias),  B=256, N=512, F=64, fp32 out.
// grid = 256 (1 block/batch/CU), block = 256 (4 waves), LDS 128 KB:
//   sft [64 o][512 k] bf16 swizzled (lower 64 KB, resident all of phase 2)
//   + 4 wave-private stripes of 2 x [16 rows x 128 k] fp32 (16 KB each).
// R13 ablation: lockstep barrier staging caps at ~5.5 TB/s vs 7.0 TB/s probe.
// Here phase 2 has ZERO s_barrier: each wave streams its own 128 adj rows
// through its own stripe (global_load_lds, depth-2, counted vmcnt), reads
// B-frags from resident sft, accumulates 16x64 per row-pass, stores, drifts.

#define BATCH 256
#define NTOK  512
#define INF   64
#define OUTF  64

typedef __attribute__((ext_vector_type(8))) __bf16 bf16x8;
typedef __attribute__((ext_vector_type(4))) __bf16 bf16x4;
typedef __attribute__((ext_vector_type(4))) float  f32x4;

typedef const __attribute__((address_space(1))) char GChar;
typedef __attribute__((address_space(3))) char LChar;

__device__ __forceinline__ bf16x8 load_cvt8(const float* __restrict__ p) {
    float4 lo = *(const float4*)p;
    float4 hi = *(const float4*)(p + 4);
    bf16x8 r;
    r[0] = (__bf16)lo.x; r[1] = (__bf16)lo.y; r[2] = (__bf16)lo.z; r[3] = (__bf16)lo.w;
    r[4] = (__bf16)hi.x; r[5] = (__bf16)hi.y; r[6] = (__bf16)hi.z; r[7] = (__bf16)hi.w;
    return r;
}

__device__ __forceinline__ bf16x8 pack8(float4 lo, float4 hi) {
    bf16x8 r;
    r[0] = (__bf16)lo.x; r[1] = (__bf16)lo.y; r[2] = (__bf16)lo.z; r[3] = (__bf16)lo.w;
    r[4] = (__bf16)hi.x; r[5] = (__bf16)hi.y; r[6] = (__bf16)hi.z; r[7] = (__bf16)hi.w;
    return r;
}

__global__ __launch_bounds__(256, 1) void GCN_fused_kernel(
        const float* __restrict__ seq, const float* __restrict__ adj,
        const float* __restrict__ W, const float* __restrict__ bias,
        const float* __restrict__ alpha_p, float* __restrict__ out) {
    __shared__ float smem[32768];            // 128 KB

    int b    = blockIdx.x;
    int tid  = threadIdx.x;
    int wave = tid >> 6;                     // 0..3; owns adj rows [wave*128, +128)
    int lane = tid & 63;
    int row16 = lane & 15;
    int g     = lane >> 4;                   // 0..3
    int rs    = row16 & 7;

    __bf16* sft = (__bf16*)smem;             // [64 o][512 k] bf16, slot-swizzled
    float* bufA = smem + 16384 + wave * 4096;   // wave-private stripe
    float* bufB = bufA + 2048;               // 2 x 8 KB = [16 x 128] fp32 each

    const float* gadj = adj + (size_t)b * NTOK * NTOK;

    // STAGE chunk CH (rows wave*128 + (CH>>2)*16, k (CH&3)*128): 8 x
    // global_load_lds, each 1 KB = 2 rows x 512 B. Load i covers rows 2i,2i+1;
    // lane: row_loc = 2i+(lane>>5), fetches swizzled slot (lane&31)^(row&7) so
    // linear LDS holds LDS[row][s] = G[row][s ^ (row&7)].
#define STAGE(dstf, CH) do {                                                   \
    int rb_ = wave * 128 + ((CH) >> 2) * 16;                                   \
    int kb_ = ((CH) & 3) * 128;                                                \
    _Pragma("unroll")                                                          \
    for (int i_ = 0; i_ < 8; ++i_) {                                           \
        int rl_ = 2 * i_ + (lane >> 5);                                        \
        int sl_ = (lane & 31) ^ (rl_ & 7);                                     \
        __builtin_amdgcn_global_load_lds(                                      \
            (GChar*)(gadj + (size_t)(rb_ + rl_) * NTOK + kb_ + sl_ * 4),       \
            (LChar*)((dstf) + i_ * 256), 16, 0, 0);                            \
    }                                                                          \
} while (0)

    STAGE(bufA, 0);                          // chunks 0,1 in flight under phase 1
    STAGE(bufB, 1);                          // (stripes don't overlap sft)
    __builtin_amdgcn_sched_barrier(0);

    // ================= Phase 1: sft[o][k] = (seq @ W^T)^T ===================
    // Wave handles tokens [wave*128, +128), all 64 o. (Verified in R8.)
    {
        int mb = wave * 128;
        bf16x8 wf[4][2];
#pragma unroll
        for (int nt = 0; nt < 4; ++nt)
#pragma unroll
            for (int ks = 0; ks < 2; ++ks)
                wf[nt][ks] = load_cvt8(W + (size_t)(nt * 16 + row16) * INF + ks * 32 + g * 8);

#pragma unroll
        for (int mt2 = 0; mt2 < 8; ++mt2) {
            f32x4 pa[4] = {};
#pragma unroll
            for (int ks = 0; ks < 2; ++ks) {
                bf16x8 af = load_cvt8(seq + ((size_t)b * NTOK + mb + mt2 * 16 + row16) * INF + ks * 32 + g * 8);
#pragma unroll
                for (int nt = 0; nt < 4; ++nt)
                    pa[nt] = __builtin_amdgcn_mfma_f32_16x16x32_bf16(af, wf[nt][ks], pa[nt], 0, 0, 0);
            }
            // D: col(o)=row16-part, row(tok)=g*4+reg. Swizzled store:
            // 16-B slot s = k>>3 stored at s ^ (o&7), within-slot offset k&7.
#pragma unroll
            for (int nt = 0; nt < 4; ++nt) {
                int o    = nt * 16 + row16;
                int ktok = mb + mt2 * 16 + g * 4;
                int sw   = (ktok >> 3) ^ (o & 7);
                bf16x4 v;
                v[0] = (__bf16)pa[nt][0]; v[1] = (__bf16)pa[nt][1];
                v[2] = (__bf16)pa[nt][2]; v[3] = (__bf16)pa[nt][3];
                *(bf16x4*)((char*)sft + (size_t)o * 1024 + sw * 16 + (ktok & 7) * 2) = v;
            }
        }
    }
    float bvv[4];
#pragma unroll
    for (int ct = 0; ct < 4; ++ct) bvv[ct] = bias[ct * 16 + row16];
    float alphav = alpha_p[0];
    __syncthreads();                         // sft visible to all; ONLY barrier

    // ================= Phase 2: 32 wave-private chunks, no barriers =========
    // chunk ch = rp*4 + kc (rp = 16-row pass 0..7, kc = 128-k chunk 0..3).
    // Body ch: drain G(ch) [counted], 16 MFMA from stripe + sft, store at
    // kc==3, then issue G(ch+2) (same-parity buf, reads already retired).
    f32x4 acc[4];
#pragma unroll
    for (int ct = 0; ct < 4; ++ct) {
        acc[ct][0] = bvv[ct]; acc[ct][1] = bvv[ct];
        acc[ct][2] = bvv[ct]; acc[ct][3] = bvv[ct];
    }

#pragma unroll
    for (int ch = 0; ch < 32; ++ch) {
        float* cur = (ch & 1) ? bufB : bufA;

        // drain G(ch). Audited after-sets: ch==0: [G1]=8; ch%4==0,ch>=4:
        // [St + G(ch+1)]=24; ch==31: []=0; else [G(ch+1)]=8.
        if (ch == 0)                        asm volatile("s_waitcnt vmcnt(8)"  ::: "memory");
        else if (ch == 31)                  asm volatile("s_waitcnt vmcnt(0)"  ::: "memory");
        else if ((ch & 3) == 0)             asm volatile("s_waitcnt vmcnt(24)" ::: "memory");
        else                                asm volatile("s_waitcnt vmcnt(8)"  ::: "memory");
        __builtin_amdgcn_sched_barrier(0);

        // compute: rows [wave*128+(ch>>2)*16, +16) x all 64 o, k-chunk ch&3.
#pragma unroll
        for (int t = 0; t < 4; ++t) {        // ktile within chunk (k = t*32)
            int sw = (t * 8 + g * 2) ^ rs;   // 16-B slot in the 32-slot row
            float4 f0 = *(const float4*)(cur + row16 * 128 + sw * 4);
            float4 f1 = *(const float4*)(cur + row16 * 128 + (sw ^ 1) * 4);
            bf16x8 a = pack8(f0, f1);
#pragma unroll
            for (int ct = 0; ct < 4; ++ct) { // col-tile: o in [ct*16, +16)
                int slot = (((ch & 3) * 4 + t) * 4 + g) ^ rs;   // sft k-slot
                bf16x8 bb = *(const bf16x8*)((const char*)sft
                              + (size_t)(ct * 16 + row16) * 1024 + slot * 16);
                acc[ct] = __builtin_amdgcn_mfma_f32_16x16x32_bf16(a, bb, acc[ct], 0, 0, 0);
            }
        }
        __builtin_amdgcn_sched_barrier(0);

        if ((ch & 3) == 3) {                 // row-pass complete: PReLU + store
            int rp = ch >> 2;
#pragma unroll
            for (int ct = 0; ct < 4; ++ct) {
#pragma unroll
                for (int j = 0; j < 4; ++j) {   // C/D row = g*4 + j
                    float v = acc[ct][j];
                    out[((size_t)b * NTOK + wave * 128 + rp * 16 + g * 4 + j) * OUTF
                        + ct * 16 + row16] = (v >= 0.f) ? v : alphav * v;
                }
                acc[ct][0] = bvv[ct]; acc[ct][1] = bvv[ct];
                acc[ct][2] = bvv[ct]; acc[ct][3] = bvv[ct];
            }
        }
        __builtin_amdgcn_sched_barrier(0);
        if (ch + 2 <= 31) STAGE(((ch & 1) ? bufB : bufA), ch + 2);
        __builtin_amdgcn_sched_barrier(0);
    }
#undef STAGE
}

extern "C" void kernel_launch(void* const* d_in, const int* in_sizes, int n_in,
                              void* d_out, int out_size, void* d_ws, size_t ws_size,
                              hipStream_t stream) {
    const float* seq   = (const float*)d_in[0];
    const float* adj   = (const float*)d_in[1];
    const float* W     = (const float*)d_in[2];
    const float* bias  = (const float*)d_in[3];
    const float* alpha = (const float*)d_in[4];
    float* out = (float*)d_out;

    GCN_fused_kernel<<<dim3(BATCH), dim3(256), 0, stream>>>(seq, adj, W, bias, alpha, out);
}

// Round 15
// 68.662 us; speedup vs baseline: 1.7317x; 1.0774x over previous
//
#include <hip/hip_runtime.h>
#include <hip/hip_bf16.h>

// GCN forward FUSED v7: out = PReLU(adj @ (seq @ W^T) + bias)
// B=256, N=512, F=64. grid=256 (1 block/batch/CU), block=512 (8 waves), 128KB LDS.
// R13 counters: WRITE_SIZE = 2.04x output size -> partial-line stores cause
// L2 read-modify-write (~68 MB extra traffic ~ 14us). v7 retiles phase 2 so
// each wave owns 16 rows x 32 cols; a ds_bpermute in-wave retile turns the
// MFMA fragment into lane-pairs of consecutive cols -> every store instr
// writes full 128-B lines (16 lanes x float2 per row-segment).
// Chunks: 16 x [64 rows x 256 k] fp32 (64 KB), (rg,kh) with acc across kh.
// Staging: global_load_lds (R6-proven), depth-1, counted vmcnt (audited:
// even it>=2 ->12, odd ->8, it0 ->8, it15 ->0). buf1 overlays sft.

#define BATCH 256
#define NTOK  512
#define INF   64
#define OUTF  64

typedef __attribute__((ext_vector_type(8))) __bf16 bf16x8;
typedef __attribute__((ext_vector_type(4))) __bf16 bf16x4;
typedef __attribute__((ext_vector_type(4))) float  f32x4;

typedef const __attribute__((address_space(1))) char GChar;
typedef __attribute__((address_space(3))) char LChar;

__device__ __forceinline__ bf16x8 load_cvt8(const float* __restrict__ p) {
    float4 lo = *(const float4*)p;
    float4 hi = *(const float4*)(p + 4);
    bf16x8 r;
    r[0] = (__bf16)lo.x; r[1] = (__bf16)lo.y; r[2] = (__bf16)lo.z; r[3] = (__bf16)lo.w;
    r[4] = (__bf16)hi.x; r[5] = (__bf16)hi.y; r[6] = (__bf16)hi.z; r[7] = (__bf16)hi.w;
    return r;
}

__device__ __forceinline__ bf16x8 pack8(float4 lo, float4 hi) {
    bf16x8 r;
    r[0] = (__bf16)lo.x; r[1] = (__bf16)lo.y; r[2] = (__bf16)lo.z; r[3] = (__bf16)lo.w;
    r[4] = (__bf16)hi.x; r[5] = (__bf16)hi.y; r[6] = (__bf16)hi.z; r[7] = (__bf16)hi.w;
    return r;
}

__global__ __launch_bounds__(512, 2) void GCN_fused_kernel(
        const float* __restrict__ seq, const float* __restrict__ adj,
        const float* __restrict__ W, const float* __restrict__ bias,
        const float* __restrict__ alpha_p, float* __restrict__ out) {
    __shared__ float smem[32768];            // 128 KB

    int b    = blockIdx.x;
    int tid  = threadIdx.x;
    int wave = tid >> 6;                     // 0..7
    int lane = tid & 63;
    int row16 = lane & 15;
    int g     = lane >> 4;                   // 0..3
    int mt    = wave >> 1;                   // 0..3: rows [mt*16, +16) of 64-row group
    int c2    = wave & 1;                    // 0/1:  cols [c2*32, +32)
    int rs    = row16 & 7;

    __bf16* sft = (__bf16*)smem;             // [64 o][512 k] bf16 (lower 64 KB)
    float* buf0 = smem + 16384;              // even chunks (kh=0), upper 64 KB
    float* buf1 = smem;                      // odd chunks (kh=1), overlays sft

    const float* gadj = adj + (size_t)b * NTOK * NTOK;

    // STAGE chunk (RG, KH): 64 rows x 256 k fp32 = 64 x 1-KB loads, 8/wave.
    // Load idx_ = row (wave*8+i). Lane fetches swizzled 16-B slot
    // (lane ^ (row&7)) of the row's 1-KB span so linear LDS holds
    // LDS[row][s] = G[row][KH*256 + 4*(s ^ (row&7))].
#define STAGE(dstf, RG, KH) do {                                               \
    _Pragma("unroll")                                                          \
    for (int i_ = 0; i_ < 8; ++i_) {                                           \
        int idx_ = wave * 8 + i_;                                              \
        __builtin_amdgcn_global_load_lds(                                      \
            (GChar*)(gadj + (size_t)((RG) * 64 + idx_) * NTOK + (KH) * 256     \
                     + ((lane ^ (idx_ & 7)) << 2)),                            \
            (LChar*)((dstf) + idx_ * 256), 16, 0, 0);                          \
    }                                                                          \
} while (0)

    STAGE(buf0, 0, 0);                       // chunk (0,0) in flight under phase 1
    __builtin_amdgcn_sched_barrier(0);

    // ================= Phase 1: sft[o][k] = (seq @ W^T)^T ===================
    {
        int mb = wave * 64;
        bf16x8 wf[4][2];
#pragma unroll
        for (int nt = 0; nt < 4; ++nt)
#pragma unroll
            for (int ks = 0; ks < 2; ++ks)
                wf[nt][ks] = load_cvt8(W + (size_t)(nt * 16 + row16) * INF + ks * 32 + g * 8);

#pragma unroll
        for (int mt2 = 0; mt2 < 4; ++mt2) {
            f32x4 pa[4] = {};
#pragma unroll
            for (int ks = 0; ks < 2; ++ks) {
                bf16x8 af = load_cvt8(seq + ((size_t)b * NTOK + mb + mt2 * 16 + row16) * INF + ks * 32 + g * 8);
#pragma unroll
                for (int nt = 0; nt < 4; ++nt)
                    pa[nt] = __builtin_amdgcn_mfma_f32_16x16x32_bf16(af, wf[nt][ks], pa[nt], 0, 0, 0);
            }
            // D: col(o)=row16-part, row(tok)=g*4+reg. Swizzled store:
            // 16-B slot s = k>>3 stored at s ^ (o&7), within-slot offset k&7.
#pragma unroll
            for (int nt = 0; nt < 4; ++nt) {
                int o    = nt * 16 + row16;
                int ktok = mb + mt2 * 16 + g * 4;
                int sw   = (ktok >> 3) ^ (o & 7);
                bf16x4 v;
                v[0] = (__bf16)pa[nt][0]; v[1] = (__bf16)pa[nt][1];
                v[2] = (__bf16)pa[nt][2]; v[3] = (__bf16)pa[nt][3];
                *(bf16x4*)((char*)sft + (size_t)o * 1024 + sw * 16 + (ktok & 7) * 2) = v;
            }
        }
    }
    float bv2[2];
#pragma unroll
    for (int ti = 0; ti < 2; ++ti) bv2[ti] = bias[c2 * 32 + ti * 16 + row16];
    float alphav = alpha_p[0];
    __syncthreads();

    // ==== Redistribute: B-frags for this wave's 32 cols, ALL K (128 VGPR) ===
    // bbr2[t][ti] = frag of sft[c2*32+ti*16+row16][k=t*32..+32]; slot t*4+g ^ rs.
    bf16x8 bbr2[16][2];
#pragma unroll
    for (int t = 0; t < 16; ++t)
#pragma unroll
        for (int ti = 0; ti < 2; ++ti) {
            int o  = c2 * 32 + ti * 16 + row16;
            int sw = ((t << 2) + g) ^ rs;
            bbr2[t][ti] = *(const bf16x8*)((const char*)sft + (size_t)o * 1024 + sw * 16);
        }
    __syncthreads();                         // sft consumed; buf1 reusable

    // ================= Phase 2: 8 row-groups x 2 k-halves ===================
    f32x4 acc2[2];
#pragma unroll
    for (int ti = 0; ti < 2; ++ti) {
        acc2[ti][0] = bv2[ti]; acc2[ti][1] = bv2[ti];
        acc2[ti][2] = bv2[ti]; acc2[ti][3] = bv2[ti];
    }

    // COMPUTE k-half KH of the current 64-row group from `curf`.
    // A-row r = mt*16+row16 (1 KB in LDS); k-step tt: slot s = tt*8+g*2 (even),
    // swizzled s^rs, partner (s^rs)^1. MFMA vs bbr2[KH*8+tt][ti].
#define COMPUTE(curf, KH) do {                                                 \
    int rowb_ = (mt * 16 + row16) * 256;                                       \
    _Pragma("unroll")                                                          \
    for (int tt_ = 0; tt_ < 8; ++tt_) {                                        \
        int s0_ = ((tt_ * 8 + g * 2) ^ rs);                                    \
        float4 f0_ = *(const float4*)((curf) + rowb_ + s0_ * 4);               \
        float4 f1_ = *(const float4*)((curf) + rowb_ + (s0_ ^ 1) * 4);         \
        bf16x8 a_ = pack8(f0_, f1_);                                           \
        acc2[0] = __builtin_amdgcn_mfma_f32_16x16x32_bf16(a_, bbr2[(KH) * 8 + tt_][0], acc2[0], 0, 0, 0); \
        acc2[1] = __builtin_amdgcn_mfma_f32_16x16x32_bf16(a_, bbr2[(KH) * 8 + tt_][1], acc2[1], 0, 0, 0); \
    }                                                                          \
} while (0)

#pragma unroll 1
    for (int rg = 0; rg < 8; ++rg) {
        // ---------- even body: it = 2*rg, chunk (rg, kh=0) in buf0 ----------
        if (rg > 0) {                        // all waves done reading buf0's old chunk
            __builtin_amdgcn_sched_barrier(0);
            __builtin_amdgcn_s_barrier();
            __builtin_amdgcn_sched_barrier(0);
        }
        STAGE(buf1, rg, 1);                  // chunk (rg,1)
        __builtin_amdgcn_sched_barrier(0);
        // newer than c_it: [St(prev odd) 4 if rg>0] + [c_{it+1} 8]
        if (rg == 0) asm volatile("s_waitcnt vmcnt(8)"  ::: "memory");
        else         asm volatile("s_waitcnt vmcnt(12)" ::: "memory");
        __builtin_amdgcn_sched_barrier(0);
        __builtin_amdgcn_s_barrier();
        __builtin_amdgcn_sched_barrier(0);
        COMPUTE(buf0, 0);

        // ---------- odd body: it = 2*rg+1, chunk (rg, kh=1) in buf1 ---------
        __builtin_amdgcn_sched_barrier(0);
        __builtin_amdgcn_s_barrier();        // all waves done reading buf0's chunk
        __builtin_amdgcn_sched_barrier(0);
        if (rg < 7) STAGE(buf0, rg + 1, 0);  // chunk (rg+1,0)
        __builtin_amdgcn_sched_barrier(0);
        if (rg < 7) asm volatile("s_waitcnt vmcnt(8)" ::: "memory");
        else        asm volatile("s_waitcnt vmcnt(0)" ::: "memory");
        __builtin_amdgcn_sched_barrier(0);
        __builtin_amdgcn_s_barrier();
        __builtin_amdgcn_sched_barrier(0);
        COMPUTE(buf1, 1);

        // ---- finalize row-group: PReLU + in-wave retile + full-line store --
        // Frag: lane(g,row16) holds cols {c2*32+row16, c2*32+16+row16} of row
        // m = rg*64+mt*16+g*4+j. Retile via ds_bpermute so lane holds cols
        // {2*row16, 2*row16+1}: per store instr 16 lanes x float2 = 128 B.
        {
            float p0[4], p1[4];
#pragma unroll
            for (int j = 0; j < 4; ++j) {
                float v0 = acc2[0][j]; p0[j] = (v0 >= 0.f) ? v0 : alphav * v0;
                float v1 = acc2[1][j]; p1[j] = (v1 >= 0.f) ? v1 : alphav * v1;
            }
            int addrA = (g * 16 + ((2 * row16) & 15)) << 2;
            int addrB = (g * 16 + ((2 * row16 + 1) & 15)) << 2;
            bool loSel = (row16 < 8);        // cols < 16 come from acc2[0]
#pragma unroll
            for (int j = 0; j < 4; ++j) {
                int a0 = __builtin_amdgcn_ds_bpermute(addrA, __float_as_int(p0[j]));
                int a1 = __builtin_amdgcn_ds_bpermute(addrA, __float_as_int(p1[j]));
                int b0 = __builtin_amdgcn_ds_bpermute(addrB, __float_as_int(p0[j]));
                int b1 = __builtin_amdgcn_ds_bpermute(addrB, __float_as_int(p1[j]));
                float lo = __int_as_float(loSel ? a0 : a1);
                float hi = __int_as_float(loSel ? b0 : b1);
                float2 st = make_float2(lo, hi);
                *(float2*)(out + ((size_t)b * NTOK + rg * 64 + mt * 16 + g * 4 + j) * OUTF
                           + c2 * 32 + 2 * row16) = st;
                acc2[0][j] = bv2[0];         // re-init for next row-group
                acc2[1][j] = bv2[1];
            }
        }
    }
#undef STAGE
#undef COMPUTE
}

extern "C" void kernel_launch(void* const* d_in, const int* in_sizes, int n_in,
                              void* d_out, int out_size, void* d_ws, size_t ws_size,
                              hipStream_t stream) {
    const float* seq   = (const float*)d_in[0];
    const float* adj   = (const float*)d_in[1];
    const float* W     = (const float*)d_in[2];
    const float* bias  = (const float*)d_in[3];
    const float* alpha = (const float*)d_in[4];
    float* out = (float*)d_out;

    GCN_fused_kernel<<<dim3(BATCH), dim3(512), 0, stream>>>(seq, adj, W, bias, alpha, out);
}